// Round 1
// 99.030 us; speedup vs baseline: 1.0538x; 1.0538x over previous
//
#include <hip/hip_runtime.h>

// Fast discrete Radon transform (exact, wrap-around shears), radix-16:
//   case A (m<512):   R_m[t]  = sum_y img[(t - m*y) & 511, y]
//   case B (m>=512):  R'_a[t] = sum_x img[x, (t - 2a*x) & 511], a = m-512
// out = R * (1/sqrt(512)), imag exactly 0.
//
// D_q[c][w][x] = sum_{u<q} A'[u*h+w][(x - c*u*h) & 511],  h = 512/q
// D_{16q}[C][w][x] = sum_{b<16} D_q[C mod q][w + b*H][(x - C*b*H) & 511]
// Stages: 1 ->(init, radix-2, case A only) 2 ->(radix-16) 32 ->(radix-16, fused output) 512.
// Case B: radix-2 fused into pass1's staging loads (no B0 buffer).

#define NN 512
#define MU 768
#define MASK 511
#define SCALE 0.04419417382415922f  // 1/sqrt(512)

// ---- init: case A transpose + radix-2; every img element read exactly once.
// Block = (x-tile pair {x0, x0+256}) x (64-wide w tile). float4 on both
// global sides; LDS stride 65 keeps the transposed read conflict-free.
__global__ __launch_bounds__(512) void k_init(const float* __restrict__ img,
                                              float* __restrict__ A0) {
  __shared__ float T[3][64][65];
  const int bx = blockIdx.x, b = blockIdx.y;
  const int xp = bx >> 2, wt = bx & 3;
  const int x0 = xp * 64, x1 = x0 + 256, w0 = wt * 64;
  const float* src = img + (size_t)b * NN * NN;
  float* dst = A0 + (size_t)b * (512 * NN);

  auto load_tile = [&](int tile, int xb, int wb, int idx) {
    const int r = (idx >> 4) & 63, c4 = (idx & 15) << 2;
    const float4 v = *(const float4*)&src[(size_t)(xb + r) * NN + wb + c4];
    T[tile][r][c4]     = v.x;
    T[tile][r][c4 + 1] = v.y;
    T[tile][r][c4 + 2] = v.z;
    T[tile][r][c4 + 3] = v.w;
  };
  auto store2 = [&](const float (*Ta)[65], const float (*Tb)[65], int rbase,
                    int cbase) {
    for (int idx = threadIdx.x; idx < 1024; idx += 512) {
      const int wl = idx >> 4, x4 = (idx & 15) << 2;
      float4 a;
      a.x = Ta[x4][wl]     + Tb[x4][wl];
      a.y = Ta[x4 + 1][wl] + Tb[x4 + 1][wl];
      a.z = Ta[x4 + 2][wl] + Tb[x4 + 2][wl];
      a.w = Ta[x4 + 3][wl] + Tb[x4 + 3][wl];
      *(float4*)&dst[(size_t)(rbase + wl) * NN + cbase + x4] = a;
    }
  };

  // phase 1: T0=(x0,w0) "T1a", T1=(x0,w0+256) "T2a", T2=(x1,w0+256) "T2b"
  for (int idx = threadIdx.x; idx < 3072; idx += 512) {
    const int tile = idx >> 10;
    load_tile(tile, (tile == 2) ? x1 : x0, (tile == 0) ? w0 : w0 + 256, idx);
  }
  __syncthreads();
  store2(T[0], T[1], w0, x0);        // class0 @ x0 = T1a + T2a
  store2(T[0], T[2], 256 + w0, x0);  // class1 @ x0 = T1a + T2b  ((x-256)&511 -> x1)
  __syncthreads();
  // phase 2: T0 <- (x1, w0) "T1b" (overwrites T1a, no longer needed)
  for (int idx = threadIdx.x; idx < 1024; idx += 512) load_tile(0, x1, w0, idx);
  __syncthreads();
  store2(T[0], T[2], w0, x1);        // class0 @ x1 = T1b + T2b
  store2(T[0], T[1], 256 + w0, x1);  // class1 @ x1 = T1b + T2a  ((x-256)&511 -> x0)
}

// ---- pass 1: stage 2 -> 32 (H=16, shifts %16==0 -> float4 LDS reads).
// Case B stages directly from img with the radix-2 row-sum fused into the
// coalesced staging loads (B0 eliminated).
__global__ __launch_bounds__(512) void k_pass1(const float* __restrict__ A0,
                                               const float* __restrict__ img,
                                               float* __restrict__ A1,
                                               float* __restrict__ B1) {
  __shared__ float L[16 * 512];
  const int bx = blockIdx.x, b = blockIdx.y;
  const int t = threadIdx.x;
  const bool isB = bx >= 32;
  const int c = isB ? 0 : (bx >> 4);
  const int w = isB ? (bx - 32) : (bx & 15);
  if (isB) {
    const float4* s4 = (const float4*)(img + (size_t)b * NN * NN);
    float4* l4 = (float4*)L;
    for (int it = 0; it < 4; ++it) {
      int flat = it * 512 + t;  // 2048 float4
      int lrow = flat >> 7, col = flat & 127;
      float4 u = s4[(w + 16 * lrow) * 128 + col];
      float4 v = s4[(w + 16 * lrow + 256) * 128 + col];
      u.x += v.x; u.y += v.y; u.z += v.z; u.w += v.w;
      l4[lrow * 128 + col] = u;
    }
  } else {
    const float4* s4 = (const float4*)(A0 + (size_t)b * 512 * NN);
    float4* l4 = (float4*)L;
    const int pbase = c * 256 + w;  // parent row bb: pbase + 16*bb
    for (int it = 0; it < 4; ++it) {
      int flat = it * 512 + t;  // 2048 float4
      int lrow = flat >> 7, col = flat & 127;
      l4[lrow * 128 + col] = s4[(pbase + 16 * lrow) * 128 + col];
    }
  }
  __syncthreads();
  const int g = t >> 7;            // 0..3
  const int x4 = (t & 127) * 4;
  float* outA = A1 + (size_t)b * 512 * NN;
  float* outB = B1 + (size_t)b * 256 * NN;
  for (int jj = 0; jj < 4; ++jj) {
    const int j = jj * 4 + g;
    const int C = isB ? (2 * j) : (c + 2 * j);
    float4 acc = {0.f, 0.f, 0.f, 0.f};
#pragma unroll
    for (int bb = 0; bb < 16; ++bb) {
      int base = (x4 - C * bb * 16) & MASK;  // %4==0: no wrap split
      float4 v = *(const float4*)&L[bb * 512 + base];
      acc.x += v.x; acc.y += v.y; acc.z += v.z; acc.w += v.w;
    }
    const int orow = isB ? (j * 16 + w) : (C * 16 + w);
    float* op = isB ? outB : outA;
    *(float4*)&op[(size_t)orow * NN + x4] = acc;
  }
}

// ---- pass 2: stage 32 -> 512 (H=1) + fused scale/float2 output -----------
__global__ __launch_bounds__(512) void k_pass2(const float* __restrict__ A1,
                                               const float* __restrict__ B1,
                                               float2* __restrict__ out) {
  __shared__ float L[16 * 512];
  const int bx = blockIdx.x, b = blockIdx.y;
  const int t = threadIdx.x;  // = x
  const bool isB = bx >= 32;
  const int c = isB ? 2 * (bx - 32) : bx;
  const float* in = isB ? (B1 + (size_t)b * 256 * NN + (size_t)(c >> 1) * 16 * NN)
                        : (A1 + (size_t)b * 512 * NN + (size_t)c * 16 * NN);
  {
    const float4* s4 = (const float4*)in;
    float4* l4 = (float4*)L;
    for (int it = 0; it < 4; ++it) l4[it * 512 + t] = s4[it * 512 + t];
  }
  __syncthreads();
  float acc[16];
#pragma unroll
  for (int j = 0; j < 16; ++j) acc[j] = 0.f;
#pragma unroll
  for (int bb = 0; bb < 16; ++bb) {
    int base = (t - c * bb) & MASK;
    const int step = (32 * bb) & MASK;
    const float* row = L + bb * 512;
#pragma unroll
    for (int j = 0; j < 16; ++j) {
      acc[j] += row[base];          // consecutive lanes -> consecutive banks
      base = (base - step) & MASK;  // shift for C = c + 32*(j+1)
    }
  }
#pragma unroll
  for (int j = 0; j < 16; ++j) {
    int m = isB ? (512 + (c >> 1) + 16 * j) : (c + 32 * j);
    float2 o; o.x = acc[j] * SCALE; o.y = 0.f;
    out[((size_t)b * MU + m) * NN + t] = o;
  }
}

// ================= fallback: round-1 direct shear-sum =====================
#define TM 16
#define YT 16
#define LDS_STRIDE 516
__global__ __launch_bounds__(512) void drt_main(const float* __restrict__ img,
                                                float* __restrict__ out) {
  __shared__ float rows[YT * LDS_STRIDE];
  const int b = blockIdx.y;
  const int tile = blockIdx.x;
  const int t = threadIdx.x;
  const bool caseB = (tile >= 32);
  const int a0 = caseB ? (tile - 32) * TM : tile * TM;
  const float* __restrict__ src = img + (size_t)b * (NN * NN);
  const int slope0 = caseB ? (2 * a0) : a0;
  const int dslope = caseB ? 2 : 1;
  float acc[TM];
#pragma unroll
  for (int i = 0; i < TM; ++i) acc[i] = 0.0f;
  for (int y0 = 0; y0 < NN; y0 += YT) {
    __syncthreads();
    if (caseB) {
#pragma unroll
      for (int r = 0; r < YT; ++r) rows[r * LDS_STRIDE + t] = src[(y0 + r) * NN + t];
    } else {
#pragma unroll
      for (int rep = 0; rep < YT; ++rep) {
        int idx = rep * NN + t;
        int xx = idx >> 4, cc = idx & 15;
        rows[cc * LDS_STRIDE + xx] = src[xx * NN + y0 + cc];
      }
    }
    __syncthreads();
#pragma unroll 4
    for (int r = 0; r < YT; ++r) {
      const int v = y0 + r;
      int base = t - slope0 * v;
      const int step = dslope * v;
      const float* __restrict__ rowp = rows + r * LDS_STRIDE;
#pragma unroll
      for (int i = 0; i < TM; ++i) { acc[i] += rowp[base & MASK]; base -= step; }
    }
  }
  const int m = caseB ? (NN + a0) : a0;
  float2* outp = (float2*)out;
#pragma unroll
  for (int i = 0; i < TM; ++i) {
    float2 vv; vv.x = acc[i] * SCALE; vv.y = 0.0f;
    outp[((size_t)b * MU + (m + i)) * NN + t] = vv;
  }
}

extern "C" void kernel_launch(void* const* d_in, const int* in_sizes, int n_in,
                              void* d_out, int out_size, void* d_ws, size_t ws_size,
                              hipStream_t stream) {
  const float* img = (const float*)d_in[0];
  if (ws_size < (size_t)42 * 1024 * 1024) {
    drt_main<<<dim3(48, 16), dim3(512), 0, stream>>>(img, (float*)d_out);
    return;
  }
  float* W  = (float*)d_ws;
  float* A0 = W;                 // 16 x 512 x 512
  float* A1 = W + 4194304;       // 16 x 512 x 512
  float* B1 = W + 8388608;       // 16 x 256 x 512

  k_init <<<dim3(16, 16), dim3(512), 0, stream>>>(img, A0);
  k_pass1<<<dim3(48, 16), dim3(512), 0, stream>>>(A0, img, A1, B1);
  k_pass2<<<dim3(48, 16), dim3(512), 0, stream>>>(A1, B1, (float2*)d_out);
}